// Round 1
// baseline (417.595 us; speedup 1.0000x reference)
//
#include <hip/hip_runtime.h>
#include <math.h>

#define INDIM 128
#define OUTDIM 64

// Kernel 1: z = h @ W ; s = z . Wa[:64] ; t = z . Wa[64:]
// One wave (64 lanes) per node; lane j owns output feature j. W staged in LDS (32 KB).
__global__ __launch_bounds__(256) void node_transform(
    const float* __restrict__ h, const float* __restrict__ W,
    const float* __restrict__ Wa, float* __restrict__ z,
    float* __restrict__ s, float* __restrict__ t, int N)
{
    __shared__ float Wl[INDIM * OUTDIM];
    for (int idx = threadIdx.x; idx < INDIM * OUTDIM; idx += 256)
        Wl[idx] = W[idx];
    __syncthreads();

    int wave = threadIdx.x >> 6;
    int lane = threadIdx.x & 63;
    int node = blockIdx.x * 4 + wave;
    if (node >= N) return;

    const float* hrow = h + (size_t)node * INDIM;
    float acc = 0.f;
    #pragma unroll
    for (int k = 0; k < INDIM; ++k)
        acc += hrow[k] * Wl[k * OUTDIM + lane];
    z[(size_t)node * OUTDIM + lane] = acc;

    float sv = acc * Wa[lane];
    float tv = acc * Wa[OUTDIM + lane];
    #pragma unroll
    for (int off = 32; off > 0; off >>= 1) {
        sv += __shfl_down(sv, off, 64);
        tv += __shfl_down(tv, off, 64);
    }
    if (lane == 0) { s[node] = sv; t[node] = tv; }
}

// Kernel 2: per-edge score e = relu(s[src]+t[dst]); segment-max into m via int atomicMax
// (valid because e >= 0 so IEEE bits are monotone under int compare; m zero-initialized).
__global__ __launch_bounds__(256) void edge_max(
    const float* __restrict__ s, const float* __restrict__ t,
    const int* __restrict__ src, const int* __restrict__ dst,
    float* __restrict__ e, int* __restrict__ m_i, int E)
{
    int i = blockIdx.x * 256 + threadIdx.x;
    if (i >= E) return;
    float ev = fmaxf(s[src[i]] + t[dst[i]], 0.f);
    e[i] = ev;
    atomicMax(m_i + dst[i], __float_as_int(ev));
}

// Kernel 3: per-edge scatter. One wave per edge, lane = feature.
// out[dst] += exp(e-m[dst]) * z[src];  denom[dst] += exp(e-m[dst])
__global__ __launch_bounds__(256) void edge_scatter(
    const float* __restrict__ z, const float* __restrict__ e,
    const float* __restrict__ m, const int* __restrict__ src,
    const int* __restrict__ dst, float* __restrict__ denom,
    float* __restrict__ out, int E)
{
    int wave = threadIdx.x >> 6;
    int lane = threadIdx.x & 63;
    int edge = blockIdx.x * 4 + wave;
    if (edge >= E) return;
    int sn = src[edge], dn = dst[edge];
    float ex = __expf(e[edge] - m[dn]);
    if (lane == 0) atomicAdd(denom + dn, ex);
    atomicAdd(out + (size_t)dn * OUTDIM + lane,
              ex * z[(size_t)sn * OUTDIM + lane]);
}

// Kernel 4: out = relu(acc / denom); nodes with no incoming edges -> 0.
__global__ __launch_bounds__(256) void finalize(
    float* __restrict__ out, const float* __restrict__ denom, long total)
{
    long i = (long)blockIdx.x * 256 + threadIdx.x;
    if (i >= total) return;
    float d = denom[i >> 6];
    float v = out[i];
    out[i] = (d > 0.f) ? fmaxf(v / d, 0.f) : 0.f;
}

extern "C" void kernel_launch(void* const* d_in, const int* in_sizes, int n_in,
                              void* d_out, int out_size, void* d_ws, size_t ws_size,
                              hipStream_t stream) {
    const float* h  = (const float*)d_in[0];
    const float* W  = (const float*)d_in[1];
    const float* Wa = (const float*)d_in[2];
    const int* src  = (const int*)d_in[3];
    const int* dst  = (const int*)d_in[4];
    int N = in_sizes[0] / INDIM;
    int E = in_sizes[3];
    float* out = (float*)d_out;

    float* ws = (float*)d_ws;
    float* z     = ws;                       // N*OUTDIM
    float* s     = z + (size_t)N * OUTDIM;   // N
    float* t     = s + N;                    // N
    float* e     = t + N;                    // E
    float* m     = e + E;                    // N
    float* denom = m + N;                    // N

    hipMemsetAsync(m, 0, (size_t)N * sizeof(float), stream);
    hipMemsetAsync(denom, 0, (size_t)N * sizeof(float), stream);
    hipMemsetAsync(d_out, 0, (size_t)out_size * sizeof(float), stream);

    node_transform<<<(N + 3) / 4, 256, 0, stream>>>(h, W, Wa, z, s, t, N);
    edge_max<<<(E + 255) / 256, 256, 0, stream>>>(s, t, src, dst, e, (int*)m, E);
    edge_scatter<<<(E + 3) / 4, 256, 0, stream>>>(z, e, m, src, dst, denom, out, E);
    long total = (long)N * OUTDIM;
    finalize<<<(int)((total + 255) / 256), 256, 0, stream>>>(out, denom, total);
}

// Round 2
// 312.328 us; speedup vs baseline: 1.3370x; 1.3370x over previous
//
#include <hip/hip_runtime.h>
#include <math.h>

#define INDIM 128
#define OUTDIM 64

// Kernel 1: z = h @ W ; s = z . Wa[:64] ; t = z . Wa[64:]
// One wave per node; lane j owns output feature j. W staged in LDS.
__global__ __launch_bounds__(256) void node_transform(
    const float* __restrict__ h, const float* __restrict__ W,
    const float* __restrict__ Wa, float* __restrict__ z,
    float* __restrict__ s, float* __restrict__ t, int N)
{
    __shared__ float Wl[INDIM * OUTDIM];
    for (int idx = threadIdx.x; idx < INDIM * OUTDIM; idx += 256)
        Wl[idx] = W[idx];
    __syncthreads();

    int wave = threadIdx.x >> 6;
    int lane = threadIdx.x & 63;
    int node = blockIdx.x * 4 + wave;
    if (node >= N) return;

    const float* hrow = h + (size_t)node * INDIM;
    float acc = 0.f;
    #pragma unroll
    for (int k = 0; k < INDIM; ++k)
        acc += hrow[k] * Wl[k * OUTDIM + lane];
    z[(size_t)node * OUTDIM + lane] = acc;

    float sv = acc * Wa[lane];
    float tv = acc * Wa[OUTDIM + lane];
    #pragma unroll
    for (int off = 32; off > 0; off >>= 1) {
        sv += __shfl_down(sv, off, 64);
        tv += __shfl_down(tv, off, 64);
    }
    if (lane == 0) { s[node] = sv; t[node] = tv; }
}

// Kernel 2: histogram of dst
__global__ __launch_bounds__(256) void hist(
    const int* __restrict__ dst, int* __restrict__ counts, int E)
{
    int i = blockIdx.x * 256 + threadIdx.x;
    if (i < E) atomicAdd(counts + dst[i], 1);
}

// Kernel 3a: per-block exclusive scan (256 elems/block) + block sums
__global__ __launch_bounds__(256) void scan_blocks(
    const int* __restrict__ counts, int* __restrict__ offsets,
    int* __restrict__ block_sums, int N)
{
    __shared__ int tmp[256];
    int i = blockIdx.x * 256 + threadIdx.x;
    int v = (i < N) ? counts[i] : 0;
    tmp[threadIdx.x] = v;
    __syncthreads();
    for (int off = 1; off < 256; off <<= 1) {
        int add = (threadIdx.x >= off) ? tmp[threadIdx.x - off] : 0;
        __syncthreads();
        tmp[threadIdx.x] += add;
        __syncthreads();
    }
    if (i < N) offsets[i] = tmp[threadIdx.x] - v;
    if (threadIdx.x == 255) block_sums[blockIdx.x] = tmp[255];
}

// Kernel 3b: single-block exclusive scan of block sums (nb <= 256)
__global__ __launch_bounds__(256) void scan_sums(int* __restrict__ block_sums, int nb)
{
    __shared__ int tmp[256];
    int v = (threadIdx.x < nb) ? block_sums[threadIdx.x] : 0;
    tmp[threadIdx.x] = v;
    __syncthreads();
    for (int off = 1; off < 256; off <<= 1) {
        int add = (threadIdx.x >= off) ? tmp[threadIdx.x - off] : 0;
        __syncthreads();
        tmp[threadIdx.x] += add;
        __syncthreads();
    }
    if (threadIdx.x < nb) block_sums[threadIdx.x] = tmp[threadIdx.x] - v;
}

// Kernel 3c: add block offsets
__global__ __launch_bounds__(256) void scan_add(
    int* __restrict__ offsets, const int* __restrict__ block_sums, int N)
{
    int i = blockIdx.x * 256 + threadIdx.x;
    if (i < N) offsets[i] += block_sums[blockIdx.x];
}

// Kernel 4: fill CSR: srcs (permuted src ids) and es (edge scores, relu'd)
__global__ __launch_bounds__(256) void csr_fill(
    const int* __restrict__ src, const int* __restrict__ dst,
    const float* __restrict__ s, const float* __restrict__ t,
    const int* __restrict__ offsets, int* __restrict__ cursor,
    int* __restrict__ srcs, float* __restrict__ es, int E)
{
    int i = blockIdx.x * 256 + threadIdx.x;
    if (i >= E) return;
    int sn = src[i], dn = dst[i];
    int pos = offsets[dn] + atomicAdd(cursor + dn, 1);
    srcs[pos] = sn;
    es[pos] = fmaxf(s[sn] + t[dn], 0.f);
}

// Kernel 5: one wave per dst node: softmax over its edges + weighted gather of z rows.
__global__ __launch_bounds__(256) void aggregate(
    const float* __restrict__ z, const int* __restrict__ srcs,
    const float* __restrict__ es, const int* __restrict__ offsets,
    const int* __restrict__ counts, float* __restrict__ out, int N)
{
    int wave = threadIdx.x >> 6;
    int lane = threadIdx.x & 63;
    int node = blockIdx.x * 4 + wave;
    if (node >= N) return;
    int start = offsets[node];
    int deg = counts[node];

    // max over edge scores (scores >= 0 post-relu, so 0 is a safe identity)
    float mx = 0.f;
    for (int j = lane; j < deg; j += 64) mx = fmaxf(mx, es[start + j]);
    #pragma unroll
    for (int off = 32; off > 0; off >>= 1) mx = fmaxf(mx, __shfl_xor(mx, off, 64));

    // softmax denominator
    float se = 0.f;
    for (int j = lane; j < deg; j += 64) se += __expf(es[start + j] - mx);
    #pragma unroll
    for (int off = 32; off > 0; off >>= 1) se += __shfl_xor(se, off, 64);

    // weighted accumulation: lane = feature
    float acc = 0.f;
    for (int j = 0; j < deg; ++j) {
        float ex = __expf(es[start + j] - mx);
        int sn = srcs[start + j];
        acc += ex * z[(size_t)sn * OUTDIM + lane];
    }
    out[(size_t)node * OUTDIM + lane] = (deg > 0) ? fmaxf(acc / se, 0.f) : 0.f;
}

extern "C" void kernel_launch(void* const* d_in, const int* in_sizes, int n_in,
                              void* d_out, int out_size, void* d_ws, size_t ws_size,
                              hipStream_t stream) {
    const float* h  = (const float*)d_in[0];
    const float* W  = (const float*)d_in[1];
    const float* Wa = (const float*)d_in[2];
    const int* src  = (const int*)d_in[3];
    const int* dst  = (const int*)d_in[4];
    int N = in_sizes[0] / INDIM;
    int E = in_sizes[3];
    float* out = (float*)d_out;

    char* ws = (char*)d_ws;
    float* z       = (float*)ws;                ws += (size_t)N * OUTDIM * 4;
    float* s       = (float*)ws;                ws += (size_t)N * 4;
    float* t       = (float*)ws;                ws += (size_t)N * 4;
    float* es      = (float*)ws;                ws += (size_t)E * 4;
    int*   srcs    = (int*)ws;                  ws += (size_t)E * 4;
    int*   counts  = (int*)ws;                  ws += (size_t)N * 4;
    int*   offsets = (int*)ws;                  ws += (size_t)N * 4;
    int*   cursor  = (int*)ws;                  ws += (size_t)N * 4;
    int*   bsums   = (int*)ws;                  ws += 256 * 4;

    int nb = (N + 255) / 256;

    hipMemsetAsync(counts, 0, (size_t)N * sizeof(int), stream);
    hipMemsetAsync(cursor, 0, (size_t)N * sizeof(int), stream);

    node_transform<<<(N + 3) / 4, 256, 0, stream>>>(h, W, Wa, z, s, t, N);
    hist<<<(E + 255) / 256, 256, 0, stream>>>(dst, counts, E);
    scan_blocks<<<nb, 256, 0, stream>>>(counts, offsets, bsums, N);
    scan_sums<<<1, 256, 0, stream>>>(bsums, nb);
    scan_add<<<nb, 256, 0, stream>>>(offsets, bsums, N);
    csr_fill<<<(E + 255) / 256, 256, 0, stream>>>(src, dst, s, t, offsets, cursor, srcs, es, E);
    aggregate<<<(N + 3) / 4, 256, 0, stream>>>(z, srcs, es, offsets, counts, out, N);
}

// Round 3
// 264.329 us; speedup vs baseline: 1.5798x; 1.1816x over previous
//
#include <hip/hip_runtime.h>
#include <math.h>

#define INDIM 128
#define OUTDIM 64
#define NPW 8  // nodes per wave in node_transform

// Kernel 1: z = h @ W ; s = z . Wa[:64] ; t = z . Wa[64:]
// 8 nodes per wave: one LDS read of W feeds 8 FMAs; h loads are wave-uniform (scalar).
__global__ __launch_bounds__(256) void node_transform(
    const float* __restrict__ h, const float* __restrict__ W,
    const float* __restrict__ Wa, float* __restrict__ z,
    float* __restrict__ s, float* __restrict__ t, int N)
{
    __shared__ float Wl[INDIM * OUTDIM];
    for (int idx = threadIdx.x; idx < INDIM * OUTDIM; idx += 256)
        Wl[idx] = W[idx];
    __syncthreads();

    int wave = threadIdx.x >> 6;
    int lane = threadIdx.x & 63;
    int node0 = (blockIdx.x * 4 + wave) * NPW;
    if (node0 >= N) return;
    int nn = min(NPW, N - node0);

    float acc[NPW];
    #pragma unroll
    for (int n = 0; n < NPW; ++n) acc[n] = 0.f;

    const float* hbase = h + (size_t)node0 * INDIM;

    if (nn == NPW) {
        #pragma unroll 4
        for (int k = 0; k < INDIM; ++k) {
            float w = Wl[k * OUTDIM + lane];
            #pragma unroll
            for (int n = 0; n < NPW; ++n)
                acc[n] += hbase[n * INDIM + k] * w;
        }
    } else {
        for (int k = 0; k < INDIM; ++k) {
            float w = Wl[k * OUTDIM + lane];
            for (int n = 0; n < nn; ++n)
                acc[n] += hbase[n * INDIM + k] * w;
        }
    }

    float wa_s = Wa[lane], wa_t = Wa[OUTDIM + lane];
    for (int n = 0; n < nn; ++n) {
        z[(size_t)(node0 + n) * OUTDIM + lane] = acc[n];
        float sv = acc[n] * wa_s;
        float tv = acc[n] * wa_t;
        #pragma unroll
        for (int off = 32; off > 0; off >>= 1) {
            sv += __shfl_down(sv, off, 64);
            tv += __shfl_down(tv, off, 64);
        }
        if (lane == 0) { s[node0 + n] = sv; t[node0 + n] = tv; }
    }
}

// Kernel 2: histogram of dst
__global__ __launch_bounds__(256) void hist(
    const int* __restrict__ dst, int* __restrict__ counts, int E)
{
    int i = blockIdx.x * 256 + threadIdx.x;
    if (i < E) atomicAdd(counts + dst[i], 1);
}

// Kernel 3a: per-block exclusive scan (256 elems/block) + block sums
__global__ __launch_bounds__(256) void scan_blocks(
    const int* __restrict__ counts, int* __restrict__ offsets,
    int* __restrict__ block_sums, int N)
{
    __shared__ int tmp[256];
    int i = blockIdx.x * 256 + threadIdx.x;
    int v = (i < N) ? counts[i] : 0;
    tmp[threadIdx.x] = v;
    __syncthreads();
    for (int off = 1; off < 256; off <<= 1) {
        int add = (threadIdx.x >= off) ? tmp[threadIdx.x - off] : 0;
        __syncthreads();
        tmp[threadIdx.x] += add;
        __syncthreads();
    }
    if (i < N) offsets[i] = tmp[threadIdx.x] - v;
    if (threadIdx.x == 255) block_sums[blockIdx.x] = tmp[255];
}

// Kernel 3b: single-block exclusive scan of block sums (nb <= 256)
__global__ __launch_bounds__(256) void scan_sums(int* __restrict__ block_sums, int nb)
{
    __shared__ int tmp[256];
    int v = (threadIdx.x < nb) ? block_sums[threadIdx.x] : 0;
    tmp[threadIdx.x] = v;
    __syncthreads();
    for (int off = 1; off < 256; off <<= 1) {
        int add = (threadIdx.x >= off) ? tmp[threadIdx.x - off] : 0;
        __syncthreads();
        tmp[threadIdx.x] += add;
        __syncthreads();
    }
    if (threadIdx.x < nb) block_sums[threadIdx.x] = tmp[threadIdx.x] - v;
}

// Kernel 3c: add block offsets; also initialize cursor = offsets
__global__ __launch_bounds__(256) void scan_add(
    int* __restrict__ offsets, int* __restrict__ cursor,
    const int* __restrict__ block_sums, int N)
{
    int i = blockIdx.x * 256 + threadIdx.x;
    if (i < N) {
        int v = offsets[i] + block_sums[blockIdx.x];
        offsets[i] = v;
        cursor[i] = v;
    }
}

// Kernel 4: fill CSR src lists (dst-sorted permutation of src ids)
__global__ __launch_bounds__(256) void csr_fill(
    const int* __restrict__ src, const int* __restrict__ dst,
    int* __restrict__ cursor, int* __restrict__ srcs, int E)
{
    int i = blockIdx.x * 256 + threadIdx.x;
    if (i >= E) return;
    int pos = atomicAdd(cursor + dst[i], 1);
    srcs[pos] = src[i];
}

// Kernel 5: one wave per dst node: softmax over incoming edges + weighted gather.
// Fast path deg<=64: lane j owns edge j (score+exp computed once), broadcast via shfl,
// 4 independent z-row gathers in flight.
__global__ __launch_bounds__(256) void aggregate(
    const float* __restrict__ z, const int* __restrict__ srcs,
    const float* __restrict__ s, const float* __restrict__ t,
    const int* __restrict__ offsets, const int* __restrict__ counts,
    float* __restrict__ out, int N)
{
    int wave = threadIdx.x >> 6;
    int lane = threadIdx.x & 63;
    int node = blockIdx.x * 4 + wave;
    if (node >= N) return;
    int start = offsets[node];
    int deg = counts[node];
    size_t orow = (size_t)node * OUTDIM + lane;
    if (deg == 0) { out[orow] = 0.f; return; }
    float tn = t[node];

    if (deg <= 64) {
        int sn = 0; float ev = 0.f;
        if (lane < deg) { sn = srcs[start + lane]; ev = fmaxf(s[sn] + tn, 0.f); }
        // max (identity 0 safe: scores >= 0 post-relu)
        float mx = ev;
        #pragma unroll
        for (int off = 32; off; off >>= 1) mx = fmaxf(mx, __shfl_xor(mx, off, 64));
        float ex = (lane < deg) ? __expf(ev - mx) : 0.f;
        float se = ex;
        #pragma unroll
        for (int off = 32; off; off >>= 1) se += __shfl_xor(se, off, 64);

        float acc = 0.f;
        int j = 0;
        for (; j + 4 <= deg; j += 4) {
            int s0 = __shfl(sn, j, 64),     s1 = __shfl(sn, j + 1, 64);
            int s2 = __shfl(sn, j + 2, 64), s3 = __shfl(sn, j + 3, 64);
            float e0 = __shfl(ex, j, 64),     e1 = __shfl(ex, j + 1, 64);
            float e2 = __shfl(ex, j + 2, 64), e3 = __shfl(ex, j + 3, 64);
            float a0 = z[(size_t)s0 * OUTDIM + lane];
            float a1 = z[(size_t)s1 * OUTDIM + lane];
            float a2 = z[(size_t)s2 * OUTDIM + lane];
            float a3 = z[(size_t)s3 * OUTDIM + lane];
            acc += e0 * a0; acc += e1 * a1; acc += e2 * a2; acc += e3 * a3;
        }
        for (; j < deg; ++j) {
            int sj = __shfl(sn, j, 64);
            float ej = __shfl(ex, j, 64);
            acc += ej * z[(size_t)sj * OUTDIM + lane];
        }
        out[orow] = fmaxf(acc / se, 0.f);
    } else {
        // rare slow path (deg > 64): strided, recompute gathers
        float mx = 0.f;
        for (int j = lane; j < deg; j += 64) {
            int sj = srcs[start + j];
            mx = fmaxf(mx, fmaxf(s[sj] + tn, 0.f));
        }
        #pragma unroll
        for (int off = 32; off; off >>= 1) mx = fmaxf(mx, __shfl_xor(mx, off, 64));
        float se = 0.f;
        for (int j = lane; j < deg; j += 64) {
            int sj = srcs[start + j];
            se += __expf(fmaxf(s[sj] + tn, 0.f) - mx);
        }
        #pragma unroll
        for (int off = 32; off; off >>= 1) se += __shfl_xor(se, off, 64);
        float acc = 0.f;
        for (int j = 0; j < deg; ++j) {
            int sj = srcs[start + j];
            float ej = __expf(fmaxf(s[sj] + tn, 0.f) - mx);
            acc += ej * z[(size_t)sj * OUTDIM + lane];
        }
        out[orow] = fmaxf(acc / se, 0.f);
    }
}

extern "C" void kernel_launch(void* const* d_in, const int* in_sizes, int n_in,
                              void* d_out, int out_size, void* d_ws, size_t ws_size,
                              hipStream_t stream) {
    const float* h  = (const float*)d_in[0];
    const float* W  = (const float*)d_in[1];
    const float* Wa = (const float*)d_in[2];
    const int* src  = (const int*)d_in[3];
    const int* dst  = (const int*)d_in[4];
    int N = in_sizes[0] / INDIM;
    int E = in_sizes[3];
    float* out = (float*)d_out;

    char* ws = (char*)d_ws;
    float* z       = (float*)ws;  ws += (size_t)N * OUTDIM * 4;
    float* s       = (float*)ws;  ws += (size_t)N * 4;
    float* t       = (float*)ws;  ws += (size_t)N * 4;
    int*   srcs    = (int*)ws;    ws += (size_t)E * 4;
    int*   counts  = (int*)ws;    ws += (size_t)N * 4;
    int*   offsets = (int*)ws;    ws += (size_t)N * 4;
    int*   cursor  = (int*)ws;    ws += (size_t)N * 4;
    int*   bsums   = (int*)ws;    ws += 256 * 4;

    int nb = (N + 255) / 256;

    hipMemsetAsync(counts, 0, (size_t)N * sizeof(int), stream);

    node_transform<<<(N + 4 * NPW - 1) / (4 * NPW), 256, 0, stream>>>(h, W, Wa, z, s, t, N);
    hist<<<(E + 255) / 256, 256, 0, stream>>>(dst, counts, E);
    scan_blocks<<<nb, 256, 0, stream>>>(counts, offsets, bsums, N);
    scan_sums<<<1, 256, 0, stream>>>(bsums, nb);
    scan_add<<<nb, 256, 0, stream>>>(offsets, cursor, bsums, N);
    csr_fill<<<(E + 255) / 256, 256, 0, stream>>>(src, dst, cursor, srcs, E);
    aggregate<<<(N + 3) / 4, 256, 0, stream>>>(z, srcs, s, t, offsets, counts, out, N);
}

// Round 4
// 222.818 us; speedup vs baseline: 1.8742x; 1.1863x over previous
//
#include <hip/hip_runtime.h>
#include <math.h>

#define INDIM 128
#define OUTDIM 64

// Fused kernel 1: blocks [0, gemm_blocks) compute z = h@W (64x64x128 LDS-tiled fp32
// GEMM, 4x4 micro-tile/thread) + s,t epilogue. Blocks >= gemm_blocks histogram dst.
__global__ __launch_bounds__(256) void node_transform_hist(
    const float* __restrict__ h, const float* __restrict__ W,
    const float* __restrict__ Wa, float* __restrict__ z,
    float* __restrict__ s, float* __restrict__ t,
    const int* __restrict__ dst, int* __restrict__ counts,
    int N, int E, int gemm_blocks)
{
    int tid = threadIdx.x;

    if (blockIdx.x >= gemm_blocks) {
        // ---- histogram path: 512 edges per block ----
        int base = (blockIdx.x - gemm_blocks) * 512 + tid;
        if (base < E) atomicAdd(counts + dst[base], 1);
        if (base + 256 < E) atomicAdd(counts + dst[base + 256], 1);
        return;
    }

    // ---- GEMM path ----
    __shared__ __align__(16) float lds[16384];  // 64 KB: hs[64][128] | Ws[128][64]
    float* hs = lds;            // h tile, row-major [node][k]
    float* Ws = lds + 8192;     // W, row-major [k][feat]

    int node0 = blockIdx.x * 64;
    int nv = min(64, N - node0);              // valid rows in this tile

    // stage h tile (contiguous 32 KB) and W (32 KB), coalesced float4
    {
        const float4* hg = (const float4*)(h + (size_t)node0 * INDIM);
        const float4* Wg = (const float4*)W;
        float4* hs4 = (float4*)hs;
        float4* Ws4 = (float4*)Ws;
        int hvalid = nv * (INDIM / 4);        // valid float4s in h tile
        #pragma unroll
        for (int i = 0; i < 8; ++i) {
            int idx = i * 256 + tid;
            hs4[idx] = (idx < hvalid) ? hg[idx] : make_float4(0.f, 0.f, 0.f, 0.f);
            Ws4[idx] = Wg[idx];
        }
    }
    __syncthreads();

    int fg = tid & 15;          // feature group
    int ng = tid >> 4;          // node group
    int f0 = fg * 4;
    int tn = ng * 4;

    float acc[4][4];
    #pragma unroll
    for (int i = 0; i < 4; ++i)
        #pragma unroll
        for (int j = 0; j < 4; ++j) acc[i][j] = 0.f;

    #pragma unroll 4
    for (int k = 0; k < INDIM; k += 4) {
        float4 a0 = *(const float4*)&hs[(tn + 0) * INDIM + k];
        float4 a1 = *(const float4*)&hs[(tn + 1) * INDIM + k];
        float4 a2 = *(const float4*)&hs[(tn + 2) * INDIM + k];
        float4 a3 = *(const float4*)&hs[(tn + 3) * INDIM + k];
        float4 w0 = *(const float4*)&Ws[(k + 0) * OUTDIM + f0];
        float4 w1 = *(const float4*)&Ws[(k + 1) * OUTDIM + f0];
        float4 w2 = *(const float4*)&Ws[(k + 2) * OUTDIM + f0];
        float4 w3 = *(const float4*)&Ws[(k + 3) * OUTDIM + f0];
        #define STEP(av, wv) { \
            acc[0][0] += av.x * wv.x; acc[0][1] += av.x * wv.y; \
            acc[0][2] += av.x * wv.z; acc[0][3] += av.x * wv.w; }
        // expand per node row: use helper via macro over rows
        #define ROW(r, ax, ay, az, aw) { \
            acc[r][0] += ax * w0.x + ay * w1.x + az * w2.x + aw * w3.x; \
            acc[r][1] += ax * w0.y + ay * w1.y + az * w2.y + aw * w3.y; \
            acc[r][2] += ax * w0.z + ay * w1.z + az * w2.z + aw * w3.z; \
            acc[r][3] += ax * w0.w + ay * w1.w + az * w2.w + aw * w3.w; }
        ROW(0, a0.x, a0.y, a0.z, a0.w)
        ROW(1, a1.x, a1.y, a1.z, a1.w)
        ROW(2, a2.x, a2.y, a2.z, a2.w)
        ROW(3, a3.x, a3.y, a3.z, a3.w)
        #undef ROW
        #undef STEP
    }

    // z store (guarded), float4 per node row
    #pragma unroll
    for (int i = 0; i < 4; ++i) {
        int node = node0 + tn + i;
        if (node < N)
            *(float4*)&z[(size_t)node * OUTDIM + f0] =
                make_float4(acc[i][0], acc[i][1], acc[i][2], acc[i][3]);
    }

    // s,t epilogue: per-thread partial dot with Wa halves, LDS atomic reduce
    float4 was = *(const float4*)&Wa[f0];
    float4 wat = *(const float4*)&Wa[OUTDIM + f0];

    __syncthreads();            // done reading hs/Ws; safe to alias
    float* sred = lds;
    float* tred = lds + 64;
    if (tid < 64) { sred[tid] = 0.f; tred[tid] = 0.f; }
    __syncthreads();
    #pragma unroll
    for (int i = 0; i < 4; ++i) {
        float ps = acc[i][0] * was.x + acc[i][1] * was.y +
                   acc[i][2] * was.z + acc[i][3] * was.w;
        float pt = acc[i][0] * wat.x + acc[i][1] * wat.y +
                   acc[i][2] * wat.z + acc[i][3] * wat.w;
        atomicAdd(&sred[tn + i], ps);
        atomicAdd(&tred[tn + i], pt);
    }
    __syncthreads();
    if (tid < 64 && node0 + tid < N) {
        s[node0 + tid] = sred[tid];
        t[node0 + tid] = tred[tid];
    }
}

// Kernel 3a: per-block exclusive scan (256 elems/block) + block sums
__global__ __launch_bounds__(256) void scan_blocks(
    const int* __restrict__ counts, int* __restrict__ offsets,
    int* __restrict__ block_sums, int N)
{
    __shared__ int tmp[256];
    int i = blockIdx.x * 256 + threadIdx.x;
    int v = (i < N) ? counts[i] : 0;
    tmp[threadIdx.x] = v;
    __syncthreads();
    for (int off = 1; off < 256; off <<= 1) {
        int add = (threadIdx.x >= off) ? tmp[threadIdx.x - off] : 0;
        __syncthreads();
        tmp[threadIdx.x] += add;
        __syncthreads();
    }
    if (i < N) offsets[i] = tmp[threadIdx.x] - v;
    if (threadIdx.x == 255) block_sums[blockIdx.x] = tmp[255];
}

// Kernel 3b: single-block exclusive scan of block sums (nb <= 256)
__global__ __launch_bounds__(256) void scan_sums(int* __restrict__ block_sums, int nb)
{
    __shared__ int tmp[256];
    int v = (threadIdx.x < nb) ? block_sums[threadIdx.x] : 0;
    tmp[threadIdx.x] = v;
    __syncthreads();
    for (int off = 1; off < 256; off <<= 1) {
        int add = (threadIdx.x >= off) ? tmp[threadIdx.x - off] : 0;
        __syncthreads();
        tmp[threadIdx.x] += add;
        __syncthreads();
    }
    if (threadIdx.x < nb) block_sums[threadIdx.x] = tmp[threadIdx.x] - v;
}

// Kernel 3c: add block offsets; also initialize cursor = offsets
__global__ __launch_bounds__(256) void scan_add(
    int* __restrict__ offsets, int* __restrict__ cursor,
    const int* __restrict__ block_sums, int N)
{
    int i = blockIdx.x * 256 + threadIdx.x;
    if (i < N) {
        int v = offsets[i] + block_sums[blockIdx.x];
        offsets[i] = v;
        cursor[i] = v;
    }
}

// Kernel 4: fill CSR src lists (dst-sorted permutation of src ids)
__global__ __launch_bounds__(256) void csr_fill(
    const int* __restrict__ src, const int* __restrict__ dst,
    int* __restrict__ cursor, int* __restrict__ srcs, int E)
{
    int i = blockIdx.x * 256 + threadIdx.x;
    if (i >= E) return;
    int pos = atomicAdd(cursor + dst[i], 1);
    srcs[pos] = src[i];
}

// Kernel 5: one wave per dst node: softmax over incoming edges + weighted gather.
__global__ __launch_bounds__(256) void aggregate(
    const float* __restrict__ z, const int* __restrict__ srcs,
    const float* __restrict__ s, const float* __restrict__ t,
    const int* __restrict__ offsets, const int* __restrict__ counts,
    float* __restrict__ out, int N)
{
    int wave = threadIdx.x >> 6;
    int lane = threadIdx.x & 63;
    int node = blockIdx.x * 4 + wave;
    if (node >= N) return;
    int start = offsets[node];
    int deg = counts[node];
    size_t orow = (size_t)node * OUTDIM + lane;
    if (deg == 0) { out[orow] = 0.f; return; }
    float tn = t[node];

    if (deg <= 64) {
        int sn = 0; float ev = 0.f;
        if (lane < deg) { sn = srcs[start + lane]; ev = fmaxf(s[sn] + tn, 0.f); }
        float mx = ev;
        #pragma unroll
        for (int off = 32; off; off >>= 1) mx = fmaxf(mx, __shfl_xor(mx, off, 64));
        float ex = (lane < deg) ? __expf(ev - mx) : 0.f;
        float se = ex;
        #pragma unroll
        for (int off = 32; off; off >>= 1) se += __shfl_xor(se, off, 64);

        float acc = 0.f;
        int j = 0;
        for (; j + 4 <= deg; j += 4) {
            int s0 = __shfl(sn, j, 64),     s1 = __shfl(sn, j + 1, 64);
            int s2 = __shfl(sn, j + 2, 64), s3 = __shfl(sn, j + 3, 64);
            float e0 = __shfl(ex, j, 64),     e1 = __shfl(ex, j + 1, 64);
            float e2 = __shfl(ex, j + 2, 64), e3 = __shfl(ex, j + 3, 64);
            float a0 = z[(size_t)s0 * OUTDIM + lane];
            float a1 = z[(size_t)s1 * OUTDIM + lane];
            float a2 = z[(size_t)s2 * OUTDIM + lane];
            float a3 = z[(size_t)s3 * OUTDIM + lane];
            acc += e0 * a0; acc += e1 * a1; acc += e2 * a2; acc += e3 * a3;
        }
        for (; j < deg; ++j) {
            int sj = __shfl(sn, j, 64);
            float ej = __shfl(ex, j, 64);
            acc += ej * z[(size_t)sj * OUTDIM + lane];
        }
        out[orow] = fmaxf(acc / se, 0.f);
    } else {
        float mx = 0.f;
        for (int j = lane; j < deg; j += 64) {
            int sj = srcs[start + j];
            mx = fmaxf(mx, fmaxf(s[sj] + tn, 0.f));
        }
        #pragma unroll
        for (int off = 32; off; off >>= 1) mx = fmaxf(mx, __shfl_xor(mx, off, 64));
        float se = 0.f;
        for (int j = lane; j < deg; j += 64) {
            int sj = srcs[start + j];
            se += __expf(fmaxf(s[sj] + tn, 0.f) - mx);
        }
        #pragma unroll
        for (int off = 32; off; off >>= 1) se += __shfl_xor(se, off, 64);
        float acc = 0.f;
        for (int j = 0; j < deg; ++j) {
            int sj = srcs[start + j];
            float ej = __expf(fmaxf(s[sj] + tn, 0.f) - mx);
            acc += ej * z[(size_t)sj * OUTDIM + lane];
        }
        out[orow] = fmaxf(acc / se, 0.f);
    }
}

extern "C" void kernel_launch(void* const* d_in, const int* in_sizes, int n_in,
                              void* d_out, int out_size, void* d_ws, size_t ws_size,
                              hipStream_t stream) {
    const float* h  = (const float*)d_in[0];
    const float* W  = (const float*)d_in[1];
    const float* Wa = (const float*)d_in[2];
    const int* src  = (const int*)d_in[3];
    const int* dst  = (const int*)d_in[4];
    int N = in_sizes[0] / INDIM;
    int E = in_sizes[3];
    float* out = (float*)d_out;

    char* ws = (char*)d_ws;
    float* z       = (float*)ws;  ws += (size_t)N * OUTDIM * 4;
    float* s       = (float*)ws;  ws += (size_t)N * 4;
    float* t       = (float*)ws;  ws += (size_t)N * 4;
    int*   srcs    = (int*)ws;    ws += (size_t)E * 4;
    int*   counts  = (int*)ws;    ws += (size_t)N * 4;
    int*   offsets = (int*)ws;    ws += (size_t)N * 4;
    int*   cursor  = (int*)ws;    ws += (size_t)N * 4;
    int*   bsums   = (int*)ws;    ws += 256 * 4;

    int nb = (N + 255) / 256;
    int gemm_blocks = (N + 63) / 64;
    int hist_blocks = (E + 511) / 512;

    hipMemsetAsync(counts, 0, (size_t)N * sizeof(int), stream);

    node_transform_hist<<<gemm_blocks + hist_blocks, 256, 0, stream>>>(
        h, W, Wa, z, s, t, dst, counts, N, E, gemm_blocks);
    scan_blocks<<<nb, 256, 0, stream>>>(counts, offsets, bsums, N);
    scan_sums<<<1, 256, 0, stream>>>(bsums, nb);
    scan_add<<<nb, 256, 0, stream>>>(offsets, cursor, bsums, N);
    csr_fill<<<(E + 255) / 256, 256, 0, stream>>>(src, dst, cursor, srcs, E);
    aggregate<<<(N + 3) / 4, 256, 0, stream>>>(z, srcs, s, t, offsets, counts, out, N);
}

// Round 5
// 212.649 us; speedup vs baseline: 1.9638x; 1.0478x over previous
//
#include <hip/hip_runtime.h>
#include <math.h>

#define INDIM 128
#define OUTDIM 64
#define HPAD 132   // h tile row stride in floats (+4 breaks bank-conflict stride)

// Fused kernel 1: blocks [0, gemm_blocks): z = h@W 64x64x128 tile, 4x4 micro-tile.
// h tile in LDS (padded); W read from global (L1-resident, coalesced 256B/wave).
// Blocks >= gemm_blocks: histogram of dst.
__global__ __launch_bounds__(256) void node_transform_hist(
    const float* __restrict__ h, const float* __restrict__ W,
    const float* __restrict__ Wa, float* __restrict__ z,
    float* __restrict__ s, float* __restrict__ t,
    const int* __restrict__ dst, int* __restrict__ counts,
    int N, int E, int gemm_blocks)
{
    int tid = threadIdx.x;

    if (blockIdx.x >= gemm_blocks) {
        int base = (blockIdx.x - gemm_blocks) * 512 + tid;
        if (base < E) atomicAdd(counts + dst[base], 1);
        if (base + 256 < E) atomicAdd(counts + dst[base + 256], 1);
        return;
    }

    __shared__ __align__(16) float hs[64 * HPAD];  // 33.8 KB

    int node0 = blockIdx.x * 64;
    int nv = min(64, N - node0);

    // stage h tile: row n, float4 j -> hs[n*HPAD + 4j]
    {
        const float4* hg = (const float4*)(h + (size_t)node0 * INDIM);
        #pragma unroll
        for (int i = 0; i < 8; ++i) {
            int idx = i * 256 + tid;
            int n = idx >> 5, j = idx & 31;
            float4 v = (n < nv) ? hg[n * 32 + j] : make_float4(0.f, 0.f, 0.f, 0.f);
            *(float4*)&hs[n * HPAD + j * 4] = v;
        }
    }
    __syncthreads();

    int fg = tid & 15;          // feature group (4 feats)
    int ng = tid >> 4;          // node group (4 nodes)
    int f0 = fg * 4;
    int tn = ng * 4;

    float acc[4][4];
    #pragma unroll
    for (int i = 0; i < 4; ++i)
        #pragma unroll
        for (int j = 0; j < 4; ++j) acc[i][j] = 0.f;

    const float4* Wg = (const float4*)W;  // W[k][f] as float4s: Wg[k*16 + fg]

    #pragma unroll 4
    for (int k = 0; k < INDIM; k += 4) {
        float4 w0 = Wg[(k + 0) * 16 + fg];
        float4 w1 = Wg[(k + 1) * 16 + fg];
        float4 w2 = Wg[(k + 2) * 16 + fg];
        float4 w3 = Wg[(k + 3) * 16 + fg];
        float4 a0 = *(const float4*)&hs[(tn + 0) * HPAD + k];
        float4 a1 = *(const float4*)&hs[(tn + 1) * HPAD + k];
        float4 a2 = *(const float4*)&hs[(tn + 2) * HPAD + k];
        float4 a3 = *(const float4*)&hs[(tn + 3) * HPAD + k];
        #define ROW(r, ax, ay, az, aw) { \
            acc[r][0] += ax * w0.x + ay * w1.x + az * w2.x + aw * w3.x; \
            acc[r][1] += ax * w0.y + ay * w1.y + az * w2.y + aw * w3.y; \
            acc[r][2] += ax * w0.z + ay * w1.z + az * w2.z + aw * w3.z; \
            acc[r][3] += ax * w0.w + ay * w1.w + az * w2.w + aw * w3.w; }
        ROW(0, a0.x, a0.y, a0.z, a0.w)
        ROW(1, a1.x, a1.y, a1.z, a1.w)
        ROW(2, a2.x, a2.y, a2.z, a2.w)
        ROW(3, a3.x, a3.y, a3.z, a3.w)
        #undef ROW
    }

    #pragma unroll
    for (int i = 0; i < 4; ++i) {
        int node = node0 + tn + i;
        if (node < N)
            *(float4*)&z[(size_t)node * OUTDIM + f0] =
                make_float4(acc[i][0], acc[i][1], acc[i][2], acc[i][3]);
    }

    // s,t epilogue via LDS atomic reduce (alias hs)
    float4 was = *(const float4*)&Wa[f0];
    float4 wat = *(const float4*)&Wa[OUTDIM + f0];
    __syncthreads();
    float* sred = hs;
    float* tred = hs + 64;
    if (tid < 64) { sred[tid] = 0.f; tred[tid] = 0.f; }
    __syncthreads();
    #pragma unroll
    for (int i = 0; i < 4; ++i) {
        float ps = acc[i][0] * was.x + acc[i][1] * was.y +
                   acc[i][2] * was.z + acc[i][3] * was.w;
        float pt = acc[i][0] * wat.x + acc[i][1] * wat.y +
                   acc[i][2] * wat.z + acc[i][3] * wat.w;
        atomicAdd(&sred[tn + i], ps);
        atomicAdd(&tred[tn + i], pt);
    }
    __syncthreads();
    if (tid < 64 && node0 + tid < N) {
        s[node0 + tid] = sred[tid];
        t[node0 + tid] = tred[tid];
    }
}

// Kernel 2a: per-block exclusive scan (256 elems/block) + block sums
__global__ __launch_bounds__(256) void scan_blocks(
    const int* __restrict__ counts, int* __restrict__ offsets,
    int* __restrict__ block_sums, int N)
{
    __shared__ int tmp[256];
    int i = blockIdx.x * 256 + threadIdx.x;
    int v = (i < N) ? counts[i] : 0;
    tmp[threadIdx.x] = v;
    __syncthreads();
    for (int off = 1; off < 256; off <<= 1) {
        int add = (threadIdx.x >= off) ? tmp[threadIdx.x - off] : 0;
        __syncthreads();
        tmp[threadIdx.x] += add;
        __syncthreads();
    }
    if (i < N) offsets[i] = tmp[threadIdx.x] - v;
    if (threadIdx.x == 255) block_sums[blockIdx.x] = tmp[255];
}

// Kernel 2b: add global block prefix (computed in-kernel from bsums) + init cursor.
// nb <= 256 guaranteed (N <= 65536).
__global__ __launch_bounds__(256) void scan_add(
    int* __restrict__ offsets, int* __restrict__ cursor,
    const int* __restrict__ block_sums, int N, int nb)
{
    __shared__ int red[256];
    int tid = threadIdx.x;
    int v = (tid < nb && tid < (int)blockIdx.x) ? block_sums[tid] : 0;
    red[tid] = v;
    __syncthreads();
    #pragma unroll
    for (int off = 128; off; off >>= 1) {
        if (tid < off) red[tid] += red[tid + off];
        __syncthreads();
    }
    int base = red[0];
    int i = blockIdx.x * 256 + tid;
    if (i < N) {
        int o = offsets[i] + base;
        offsets[i] = o;
        cursor[i] = o;
    }
}

// Kernel 3: fill CSR src lists (dst-sorted permutation of src ids)
__global__ __launch_bounds__(256) void csr_fill(
    const int* __restrict__ src, const int* __restrict__ dst,
    int* __restrict__ cursor, int* __restrict__ srcs, int E)
{
    int i = blockIdx.x * 256 + threadIdx.x;
    if (i >= E) return;
    int pos = atomicAdd(cursor + dst[i], 1);
    srcs[pos] = src[i];
}

// Kernel 4: one wave per dst node: softmax over incoming edges + weighted gather.
__global__ __launch_bounds__(256) void aggregate(
    const float* __restrict__ z, const int* __restrict__ srcs,
    const float* __restrict__ s, const float* __restrict__ t,
    const int* __restrict__ offsets, const int* __restrict__ counts,
    float* __restrict__ out, int N)
{
    int wave = threadIdx.x >> 6;
    int lane = threadIdx.x & 63;
    int node = blockIdx.x * 4 + wave;
    if (node >= N) return;
    int start = offsets[node];
    int deg = counts[node];
    size_t orow = (size_t)node * OUTDIM + lane;
    if (deg == 0) { out[orow] = 0.f; return; }
    float tn = t[node];

    if (deg <= 64) {
        int sn = 0; float ev = 0.f;
        if (lane < deg) { sn = srcs[start + lane]; ev = fmaxf(s[sn] + tn, 0.f); }
        float mx = ev;
        #pragma unroll
        for (int off = 32; off; off >>= 1) mx = fmaxf(mx, __shfl_xor(mx, off, 64));
        float ex = (lane < deg) ? __expf(ev - mx) : 0.f;
        float se = ex;
        #pragma unroll
        for (int off = 32; off; off >>= 1) se += __shfl_xor(se, off, 64);

        float acc = 0.f;
        int j = 0;
        for (; j + 8 <= deg; j += 8) {
            int   si[8]; float ei[8]; float ai[8];
            #pragma unroll
            for (int u = 0; u < 8; ++u) {
                si[u] = __shfl(sn, j + u, 64);
                ei[u] = __shfl(ex, j + u, 64);
            }
            #pragma unroll
            for (int u = 0; u < 8; ++u)
                ai[u] = z[(size_t)si[u] * OUTDIM + lane];
            #pragma unroll
            for (int u = 0; u < 8; ++u)
                acc += ei[u] * ai[u];
        }
        for (; j + 4 <= deg; j += 4) {
            int s0 = __shfl(sn, j, 64),     s1 = __shfl(sn, j + 1, 64);
            int s2 = __shfl(sn, j + 2, 64), s3 = __shfl(sn, j + 3, 64);
            float e0 = __shfl(ex, j, 64),     e1 = __shfl(ex, j + 1, 64);
            float e2 = __shfl(ex, j + 2, 64), e3 = __shfl(ex, j + 3, 64);
            float a0 = z[(size_t)s0 * OUTDIM + lane];
            float a1 = z[(size_t)s1 * OUTDIM + lane];
            float a2 = z[(size_t)s2 * OUTDIM + lane];
            float a3 = z[(size_t)s3 * OUTDIM + lane];
            acc += e0 * a0; acc += e1 * a1; acc += e2 * a2; acc += e3 * a3;
        }
        for (; j < deg; ++j) {
            int sj = __shfl(sn, j, 64);
            float ej = __shfl(ex, j, 64);
            acc += ej * z[(size_t)sj * OUTDIM + lane];
        }
        out[orow] = fmaxf(acc / se, 0.f);
    } else {
        float mx = 0.f;
        for (int j = lane; j < deg; j += 64) {
            int sj = srcs[start + j];
            mx = fmaxf(mx, fmaxf(s[sj] + tn, 0.f));
        }
        #pragma unroll
        for (int off = 32; off; off >>= 1) mx = fmaxf(mx, __shfl_xor(mx, off, 64));
        float se = 0.f;
        for (int j = lane; j < deg; j += 64) {
            int sj = srcs[start + j];
            se += __expf(fmaxf(s[sj] + tn, 0.f) - mx);
        }
        #pragma unroll
        for (int off = 32; off; off >>= 1) se += __shfl_xor(se, off, 64);
        float acc = 0.f;
        for (int j = 0; j < deg; ++j) {
            int sj = srcs[start + j];
            float ej = __expf(fmaxf(s[sj] + tn, 0.f) - mx);
            acc += ej * z[(size_t)sj * OUTDIM + lane];
        }
        out[orow] = fmaxf(acc / se, 0.f);
    }
}

extern "C" void kernel_launch(void* const* d_in, const int* in_sizes, int n_in,
                              void* d_out, int out_size, void* d_ws, size_t ws_size,
                              hipStream_t stream) {
    const float* h  = (const float*)d_in[0];
    const float* W  = (const float*)d_in[1];
    const float* Wa = (const float*)d_in[2];
    const int* src  = (const int*)d_in[3];
    const int* dst  = (const int*)d_in[4];
    int N = in_sizes[0] / INDIM;
    int E = in_sizes[3];
    float* out = (float*)d_out;

    char* ws = (char*)d_ws;
    float* z       = (float*)ws;  ws += (size_t)N * OUTDIM * 4;
    float* s       = (float*)ws;  ws += (size_t)N * 4;
    float* t       = (float*)ws;  ws += (size_t)N * 4;
    int*   srcs    = (int*)ws;    ws += (size_t)E * 4;
    int*   counts  = (int*)ws;    ws += (size_t)N * 4;
    int*   offsets = (int*)ws;    ws += (size_t)N * 4;
    int*   cursor  = (int*)ws;    ws += (size_t)N * 4;
    int*   bsums   = (int*)ws;    ws += 256 * 4;

    int nb = (N + 255) / 256;
    int gemm_blocks = (N + 63) / 64;
    int hist_blocks = (E + 511) / 512;

    hipMemsetAsync(counts, 0, (size_t)N * sizeof(int), stream);

    node_transform_hist<<<gemm_blocks + hist_blocks, 256, 0, stream>>>(
        h, W, Wa, z, s, t, dst, counts, N, E, gemm_blocks);
    scan_blocks<<<nb, 256, 0, stream>>>(counts, offsets, bsums, N);
    scan_add<<<nb, 256, 0, stream>>>(offsets, cursor, bsums, N, nb);
    csr_fill<<<(E + 255) / 256, 256, 0, stream>>>(src, dst, cursor, srcs, E);
    aggregate<<<(N + 3) / 4, 256, 0, stream>>>(z, srcs, s, t, offsets, counts, out, N);
}